// Round 8
// baseline (257.351 us; speedup 1.0000x reference)
//
#include <hip/hip_runtime.h>
#include <stdint.h>

// S6Layer on MI355X. B=8, L=4096, DM=256, DI=384, DS=8, CHUNK=32.
// R13 (this round): FUSE GEMM2 + scan + GEMM3 into one kernel (s6_tail).
// R7 counters: GEMM1 51us (FETCH 52->24.5MB: R12 swizzle confirmed), but the
// pipeline tail (GEMM2+scan+GEMM3, ~130us incl. boundaries) moves ~100MB of
// self-inflicted intermediates (dt, yz round-trips) and pays 3 kernel drains.
// s6_tail: block=64 tokens (2 scan chunks), grid 512, LDS 48KB (2 blocks/CU):
//   Phase A: dt = softplus(dtin@Wdt^T+b_dt) -> sDT (16B-chunk XOR swizzle,
//            same scheme as sB). Waves split N 16-cols-each -> Wdt read 1x
//            per block (L2-hot). dtin direct global (L3-hot).
//   Phase B: scan; 768 units = exactly 3/thread, interleaved in one tt-loop
//            (3 independent chains ILP). yz overwrites sDT IN PLACE (each
//            (tok,di) read-then-written by one thread; disjoint across thr).
//   Phase C: GEMM3; A-frags ds_read from swizzled sDT via E/O bases (2-way
//            banks = free), B=Wout direct, + b_out + residual -> out fp32.
// 2 barriers total; dt/yz never touch global. Saves ~100MB HBM + 2 launches.
// R12 GEMM1 kept verbatim (persistent-B MT=2, XCD chunk swizzle, 1 barrier).
#define B_  8
#define L_  4096
#define DM  256
#define DI  384
#define DS  8
#define M_  (B_*L_)   // 32768 tokens

typedef float f32x4 __attribute__((ext_vector_type(4)));
typedef short s16x8 __attribute__((ext_vector_type(8)));

#define AS1(p) ((__attribute__((address_space(1))) void*)(p))
#define AS3(p) ((__attribute__((address_space(3))) void*)(p))

__device__ __forceinline__ unsigned short f2bf(float f) {
  union { float f; uint32_t u; } v; v.f = f;
  uint32_t r = v.u + 0x7FFFu + ((v.u >> 16) & 1u);   // RNE
  return (unsigned short)(r >> 16);
}
__device__ __forceinline__ float bf2f(unsigned short h) {
  union { uint32_t u; float f; } v; v.u = ((uint32_t)h) << 16;
  return v.f;
}
__device__ __forceinline__ float silu_f(float x) {
  return x * __builtin_amdgcn_rcpf(1.f + __expf(-x));
}

// ---------------- weight fp32 -> bf16 ----------------
__global__ __launch_bounds__(256) void cvt_kernel(
    const float* __restrict__ w0, const float* __restrict__ w1, const float* __restrict__ w2,
    unsigned short* __restrict__ o0, unsigned short* __restrict__ o1, unsigned short* __restrict__ o2) {
  int i = blockIdx.x * 256 + threadIdx.x;
  if (i < 3*DI*DM) o0[i] = f2bf(w0[i]);
  if (i < DI*DI)   o1[i] = f2bf(w1[i]);
  if (i < DM*DI)   o2[i] = f2bf(w2[i]);
}

// ---------------- layernorm: one wave per token ----------------
__global__ __launch_bounds__(256) void ln_kernel(
    const float* __restrict__ x, const float* __restrict__ gamma, const float* __restrict__ beta,
    unsigned short* __restrict__ xn) {
  int token = blockIdx.x * 4 + (threadIdx.x >> 6);
  int lane  = threadIdx.x & 63;
  const float4 v = *(const float4*)(x + (size_t)token*DM + lane*4);
  float s  = v.x + v.y + v.z + v.w;
  float ss = v.x*v.x + v.y*v.y + v.z*v.z + v.w*v.w;
  #pragma unroll
  for (int off = 32; off > 0; off >>= 1) {
    s  += __shfl_xor(s,  off, 64);
    ss += __shfl_xor(ss, off, 64);
  }
  float mean = s * (1.f/DM);
  float var  = ss * (1.f/DM) - mean*mean;
  float rstd = rsqrtf(var + 1e-5f);
  const float4 g = *(const float4*)(gamma + lane*4);
  const float4 b = *(const float4*)(beta  + lane*4);
  ushort4 o;
  o.x = f2bf((v.x - mean)*rstd*g.x + b.x);
  o.y = f2bf((v.y - mean)*rstd*g.y + b.y);
  o.z = f2bf((v.z - mean)*rstd*g.z + b.z);
  o.w = f2bf((v.w - mean)*rstd*g.w + b.w);
  *(ushort4*)(xn + (size_t)token*DM + lane*4) = o;
}

// ---------------- persistent-B MFMA GEMM (GEMM1), MT M-tiles per block -----
template<int EPI, int KSTEPS, int MT>
__global__ __launch_bounds__(256, 3) void gemm_ws(
    const unsigned short* __restrict__ A,   // [M,K] bf16
    const unsigned short* __restrict__ Bw,  // [N,K] bf16
    const float* __restrict__ bias,         // [N]
    unsigned short* __restrict__ o_xp, unsigned short* __restrict__ o_z,
    unsigned short* __restrict__ o_dtin,    // EPI=1
    unsigned short* __restrict__ o_bf,      // EPI=2 (unused)
    const float* __restrict__ resid, float* __restrict__ o_f)  // EPI=3 (unused)
{
  constexpr int K    = KSTEPS * 32;
  constexpr int CPR  = K / 8;               // 16B chunks per B row
  __shared__ unsigned short sB[64*K];
  __shared__ unsigned short sC[(EPI == 3) ? 2 : 4*32*72];  // wave-private C staging

  const int t    = threadIdx.x;
  const int lane = t & 63;
  const int w    = t >> 6;
  const int fr   = lane & 15;
  const int fq   = lane >> 4;
  const int wm   = w * 32;

  // ---- XCD chunk swizzle: bijective for grid (128, GY) ----
  const int q    = blockIdx.y * 128 + blockIdx.x;
  const int bx2  = (q & 7) * 16 + ((q >> 3) & 15);
  const int by2  = q >> 7;
  const int mbase0 = bx2 * (128 * MT);
  const int nbase  = by2 * 64;

  // ---- stage B panel (once per block): swizzled 16B chunks ----
  #pragma unroll
  for (int i = 0; i < (64*CPR)/256; ++i) {
    int c   = i*256 + t;
    int row = c / CPR;
    int j   = c - row*CPR;
    int jp  = (j & ~7) | ((j & 7) ^ (row & 7));
    __builtin_amdgcn_global_load_lds(AS1(Bw + (size_t)(nbase + row)*K + jp*8),
                                     AS3(sB + c*8), 16, 0, 0);
  }

  const unsigned short* sBrE = sB + (size_t)fr*K + ( fq      ^ (fr & 7))*8;
  const unsigned short* sBrO = sB + (size_t)fr*K + ((fq | 4) ^ (fr & 7))*8;

  float bvv[4];
  #pragma unroll
  for (int ni = 0; ni < 4; ++ni) bvv[ni] = bias[nbase + ni*16 + fr];

  unsigned short* sCw = sC + w*(32*72);

  __syncthreads();   // B panel resident — the ONLY barrier in this kernel

  #pragma unroll
  for (int mt = 0; mt < MT; ++mt) {
    const int mbase = mbase0 + mt*128;
    const unsigned short* gA0 = A + (size_t)(mbase + wm + fr)*K + fq*8;
    const unsigned short* gA1 = gA0 + (size_t)16*K;

    f32x4 acc[2][4];
    #pragma unroll
    for (int mi = 0; mi < 2; ++mi)
      #pragma unroll
      for (int ni = 0; ni < 4; ++ni) acc[mi][ni] = (f32x4){0.f, 0.f, 0.f, 0.f};

    #pragma unroll
    for (int kt = 0; kt < KSTEPS; ++kt) {
      s16x8 a0 = *(const s16x8*)(gA0 + kt*32);
      s16x8 a1 = *(const s16x8*)(gA1 + kt*32);
      const unsigned short* bb = (kt & 1) ? sBrO : sBrE;
      s16x8 bfr[4];
      #pragma unroll
      for (int ni = 0; ni < 4; ++ni)
        bfr[ni] = *(const s16x8*)(bb + ni*16*K + (kt >> 1)*64);
      #pragma unroll
      for (int ni = 0; ni < 4; ++ni) {
        acc[0][ni] = __builtin_amdgcn_mfma_f32_16x16x32_bf16(a0, bfr[ni], acc[0][ni], 0, 0, 0);
        acc[1][ni] = __builtin_amdgcn_mfma_f32_16x16x32_bf16(a1, bfr[ni], acc[1][ni], 0, 0, 0);
      }
    }

    if constexpr (EPI == 3) {
      #pragma unroll
      for (int ni = 0; ni < 4; ++ni) {
        int gn = nbase + ni*16 + fr;
        #pragma unroll
        for (int mi = 0; mi < 2; ++mi) {
          int gm0 = mbase + wm + mi*16 + fq*4;
          #pragma unroll
          for (int r = 0; r < 4; ++r) {
            size_t gm = (size_t)(gm0 + r);
            o_f[gm*DM + gn] = acc[mi][ni][r] + bvv[ni] + resid[gm*DM + gn];
          }
        }
      }
    } else {
      const bool do_silu = (EPI == 1) && (by2 < 12);
      #pragma unroll
      for (int ni = 0; ni < 4; ++ni) {
        int cn = ni*16 + fr;
        #pragma unroll
        for (int mi = 0; mi < 2; ++mi) {
          int rm0 = mi*16 + fq*4;
          #pragma unroll
          for (int r = 0; r < 4; ++r) {
            float c = acc[mi][ni][r] + bvv[ni];
            if constexpr (EPI == 1) { if (do_silu) c = silu_f(c); }
            else                    { c = (c > 20.f) ? c : __logf(1.f + __expf(c)); }
            sCw[(rm0 + r)*72 + cn] = f2bf(c);
          }
        }
      }
      asm volatile("s_waitcnt lgkmcnt(0)" ::: "memory");
      unsigned short* dst;
      int colbase;
      if constexpr (EPI == 1) {
        dst = (by2 < 6) ? o_xp : (by2 < 12) ? o_z : o_dtin;
        colbase = (by2 % 6) * 64;
      } else {
        dst = o_bf; colbase = nbase;
      }
      const int rr = lane >> 3, cc = (lane & 7) * 8;
      #pragma unroll
      for (int it = 0; it < 4; ++it) {
        int row32 = rr + it*8;
        s16x8 v = *(const s16x8*)(sCw + row32*72 + cc);
        *(s16x8*)(dst + (size_t)(mbase + wm + row32)*DI + colbase + cc) = v;
      }
    }
  }
}

// ---------------- fused tail: GEMM2 + chunked scan + GEMM3 -----------------
// Block = 64 tokens (2 scan chunks), 256 thr (4 waves), grid 512.
// sDT[64][384] bf16 (48KB), stored with the 16B-chunk XOR swizzle:
//   elem(row,col) at byte row*768 + swz(col>>3,row)*16 + (col&7)*2,
//   swz(j,row) = (j&~7)|((j&7)^(row&7)).
// Phase A: wave w owns cols w*16..+15 of each 64-panel (Wdt read 1x/block,
//   disjoint across waves); A=dtin direct global; acc[4] per wave per panel.
// Phase B: 768 (chunk,di) units = 3/thread, one tt-loop, ILP across units;
//   yz overwrites sDT in place (same thread reads-then-writes each slot).
// Phase C: A from sDT via E/O swizzle bases (2-way banks), B=Wout direct;
//   out = acc + b_out + resid (fp32).
__global__ __launch_bounds__(256, 2) void s6_tail(
    const unsigned short* __restrict__ dtin,
    const unsigned short* __restrict__ xp,
    const unsigned short* __restrict__ zb,
    const unsigned short* __restrict__ Wdt,   // [384,384] bf16
    const unsigned short* __restrict__ Wout,  // [256,384] bf16
    const float* __restrict__ b_dt, const float* __restrict__ b_out,
    const float* __restrict__ A_log, const float* __restrict__ D_vec,
    const float* __restrict__ resid, float* __restrict__ o_f)
{
  __shared__ unsigned short sDT[64*384];   // 48KB
  const int t    = threadIdx.x;
  const int lane = t & 63;
  const int w    = t >> 6;
  const int fr   = lane & 15;
  const int fq   = lane >> 4;
  const int wn16 = w * 16;                 // wave's col slice in each panel
  const int mbase = blockIdx.x * 64;

  // ---------- Phase A: dt = softplus(dtin @ Wdt^T + b_dt) -> sDT ----------
  const unsigned short* gA = dtin + (size_t)(mbase + fr)*DI + fq*8;
  #pragma unroll
  for (int np = 0; np < 6; ++np) {
    const unsigned short* gB = Wdt + (size_t)(np*64 + wn16 + fr)*DI + fq*8;
    float bv = b_dt[np*64 + wn16 + fr];
    f32x4 acc[4];
    #pragma unroll
    for (int mi = 0; mi < 4; ++mi) acc[mi] = (f32x4){0.f, 0.f, 0.f, 0.f};
    #pragma unroll
    for (int kt = 0; kt < 12; ++kt) {
      s16x8 bfrg = *(const s16x8*)(gB + kt*32);
      #pragma unroll
      for (int mi = 0; mi < 4; ++mi) {
        s16x8 afrg = *(const s16x8*)(gA + mi*16*DI + kt*32);
        acc[mi] = __builtin_amdgcn_mfma_f32_16x16x32_bf16(afrg, bfrg, acc[mi], 0, 0, 0);
      }
    }
    #pragma unroll
    for (int mi = 0; mi < 4; ++mi)
      #pragma unroll
      for (int r = 0; r < 4; ++r) {
        int row = mi*16 + fq*4 + r;
        int cn  = np*64 + wn16 + fr;
        float c = acc[mi][r] + bv;
        c = (c > 20.f) ? c : __logf(1.f + __expf(c));
        int j  = cn >> 3;
        int jp = (j & ~7) | ((j & 7) ^ (row & 7));
        sDT[row*DI + jp*8 + (cn & 7)] = f2bf(c);
      }
  }
  __syncthreads();

  // ---------- Phase B: chunked scan; yz -> sDT in place ----------
  {
    int   chunk[3], di[3], jb[3], del[3];
    float av[3][8], hs[3][8], Dv[3];
    const unsigned short *gx[3], *gz[3];
    #pragma unroll
    for (int i = 0; i < 3; ++i) {
      int u    = t + i*256;                 // 0..767, exact cover
      chunk[i] = (u >= 384) ? 1 : 0;
      di[i]    = u - chunk[i]*384;
      jb[i]    = di[i] >> 3;
      del[i]   = di[i] & 7;
      #pragma unroll
      for (int s = 0; s < DS; ++s) { av[i][s] = -__expf(A_log[di[i]*DS + s]); hs[i][s] = 0.f; }
      Dv[i] = D_vec[di[i]];
      gx[i] = xp + (size_t)(mbase + chunk[i]*32)*DI + di[i];
      gz[i] = zb + (size_t)(mbase + chunk[i]*32)*DI + di[i];
    }
    for (int tt = 0; tt < 32; ++tt) {
      #pragma unroll
      for (int i = 0; i < 3; ++i) {
        int tok  = chunk[i]*32 + tt;
        int jp   = (jb[i] & ~7) | ((jb[i] & 7) ^ (tok & 7));
        int sidx = tok*DI + jp*8 + del[i];
        float dtv = bf2f(sDT[sidx]);
        float xv  = bf2f(gx[i][(size_t)tt*DI]);
        float y = 0.f;
        #pragma unroll
        for (int s = 0; s < DS; ++s) {
          hs[i][s] = hs[i][s]*__expf(dtv*av[i][s]) + xv;
          y += hs[i][s];
        }
        float zv = bf2f(gz[i][(size_t)tt*DI]);
        sDT[sidx] = f2bf(y*zv + xv*Dv[i]);
      }
    }
  }
  __syncthreads();

  // ---------- Phase C: out = yz @ Wout^T + b_out + resid ----------
  const int lbE = ( fq      ^ (fr & 7))*8;
  const int lbO = ((fq | 4) ^ (fr & 7))*8;
  #pragma unroll
  for (int np = 0; np < 4; ++np) {
    const unsigned short* gB = Wout + (size_t)(np*64 + wn16 + fr)*DI + fq*8;
    float bv = b_out[np*64 + wn16 + fr];
    f32x4 acc[4];
    #pragma unroll
    for (int mi = 0; mi < 4; ++mi) acc[mi] = (f32x4){0.f, 0.f, 0.f, 0.f};
    #pragma unroll
    for (int kt = 0; kt < 12; ++kt) {
      s16x8 bfrg = *(const s16x8*)(gB + kt*32);
      int off = ((kt & 1) ? lbO : lbE) + (kt >> 1)*64;
      #pragma unroll
      for (int mi = 0; mi < 4; ++mi) {
        s16x8 afrg = *(const s16x8*)(sDT + (mi*16 + fr)*DI + off);
        acc[mi] = __builtin_amdgcn_mfma_f32_16x16x32_bf16(afrg, bfrg, acc[mi], 0, 0, 0);
      }
    }
    #pragma unroll
    for (int mi = 0; mi < 4; ++mi)
      #pragma unroll
      for (int r = 0; r < 4; ++r) {
        size_t gm = (size_t)(mbase + mi*16 + fq*4 + r);
        int gn = np*64 + wn16 + fr;
        o_f[gm*DM + gn] = acc[mi][r] + bv + resid[gm*DM + gn];
      }
  }
}

extern "C" void kernel_launch(void* const* d_in, const int* in_sizes, int n_in,
                              void* d_out, int out_size, void* d_ws, size_t ws_size,
                              hipStream_t stream) {
  const float* x     = (const float*)d_in[0];
  const float* gamma = (const float*)d_in[1];
  const float* beta  = (const float*)d_in[2];
  const float* W_in  = (const float*)d_in[3];
  const float* b_in  = (const float*)d_in[4];
  const float* W_dt  = (const float*)d_in[5];
  const float* b_dt  = (const float*)d_in[6];
  const float* A_log = (const float*)d_in[7];
  const float* D_vec = (const float*)d_in[8];
  const float* W_out = (const float*)d_in[9];
  const float* b_out = (const float*)d_in[10];
  float* out = (float*)d_out;

  char* ws = (char*)d_ws;
  size_t off = 0;
  auto alloc = [&](size_t bytes) -> char* {
    char* p = ws + off; off += (bytes + 255) & ~(size_t)255; return p;
  };
  unsigned short* xn    = (unsigned short*)alloc((size_t)M_*DM*2);
  unsigned short* xpb   = (unsigned short*)alloc((size_t)M_*DI*2);
  unsigned short* zb    = (unsigned short*)alloc((size_t)M_*DI*2);
  unsigned short* dtin  = (unsigned short*)alloc((size_t)M_*DI*2);
  unsigned short* winb  = (unsigned short*)alloc((size_t)3*DI*DM*2);
  unsigned short* wdtb  = (unsigned short*)alloc((size_t)DI*DI*2);
  unsigned short* woutb = (unsigned short*)alloc((size_t)DM*DI*2);

  cvt_kernel<<<dim3((3*DI*DM + 255)/256), 256, 0, stream>>>(W_in, W_dt, W_out, winb, wdtb, woutb);
  ln_kernel<<<dim3(M_/4), 256, 0, stream>>>(x, gamma, beta, xn);
  // GEMM1: xn[M,256] @ W_in[1152,256]^T -> silu(xp), silu(z), dtin
  gemm_ws<1, 8, 2><<<dim3(128, (3*DI)/64), 256, 0, stream>>>(
      xn, winb, b_in, xpb, zb, dtin, nullptr, nullptr, nullptr);
  // fused tail: GEMM2 + scan + GEMM3 -> out
  s6_tail<<<dim3(M_/64), 256, 0, stream>>>(
      dtin, xpb, zb, wdtb, woutb, b_dt, b_out, A_log, D_vec, x, out);
}

// Round 9
// 224.476 us; speedup vs baseline: 1.1464x; 1.1464x over previous
//
#include <hip/hip_runtime.h>
#include <stdint.h>

// S6Layer on MI355X. B=8, L=4096, DM=256, DI=384, DS=8, CHUNK=32.
// R15 (this round): R13 fusion REVERTED (s6_tail 121.6us vs ~88us unfused;
// HBM was 9% busy - saved traffic on a non-bottleneck). Back to R12 pipeline
// (cvt, ln, GEMM1, GEMM2, scan, GEMM3), with the shared GEMM template widened:
//   WAVE TILE 32x64 -> 64x64 (block tile 256x64, acc[4][4], 16 MFMA/kt).
// Rationale from R4/R7 counters: every variant sits at Mfma 12-15% with
// nothing >35% busy = per-kt load latency (~200cy) vs per-kt MFMA work
// (~39cy for 8 MFMAs). 16 MFMAs/kt amortizes the same stall over 2x math and
// halves B-frag LDS traffic per FLOP. No new fences/races (plain VGPR deps).
// Epilogue: wave-private 32x72 LDS staging, 2 passes (mi-pairs); no barriers.
// R12 kept: persistent-B (staged once/block), XCD chunk swizzle (bijective,
// grid (128,GY)), single barrier per kernel, B swizzle folded to 2 bases+imm.
#define B_  8
#define L_  4096
#define DM  256
#define DI  384
#define DS  8
#define M_  (B_*L_)   // 32768 tokens

typedef float f32x4 __attribute__((ext_vector_type(4)));
typedef short s16x8 __attribute__((ext_vector_type(8)));

#define AS1(p) ((__attribute__((address_space(1))) void*)(p))
#define AS3(p) ((__attribute__((address_space(3))) void*)(p))

__device__ __forceinline__ unsigned short f2bf(float f) {
  union { float f; uint32_t u; } v; v.f = f;
  uint32_t r = v.u + 0x7FFFu + ((v.u >> 16) & 1u);   // RNE
  return (unsigned short)(r >> 16);
}
__device__ __forceinline__ float bf2f(unsigned short h) {
  union { uint32_t u; float f; } v; v.u = ((uint32_t)h) << 16;
  return v.f;
}
__device__ __forceinline__ float silu_f(float x) {
  return x * __builtin_amdgcn_rcpf(1.f + __expf(-x));
}

// ---------------- weight fp32 -> bf16 ----------------
__global__ __launch_bounds__(256) void cvt_kernel(
    const float* __restrict__ w0, const float* __restrict__ w1, const float* __restrict__ w2,
    unsigned short* __restrict__ o0, unsigned short* __restrict__ o1, unsigned short* __restrict__ o2) {
  int i = blockIdx.x * 256 + threadIdx.x;
  if (i < 3*DI*DM) o0[i] = f2bf(w0[i]);
  if (i < DI*DI)   o1[i] = f2bf(w1[i]);
  if (i < DM*DI)   o2[i] = f2bf(w2[i]);
}

// ---------------- layernorm: one wave per token ----------------
__global__ __launch_bounds__(256) void ln_kernel(
    const float* __restrict__ x, const float* __restrict__ gamma, const float* __restrict__ beta,
    unsigned short* __restrict__ xn) {
  int token = blockIdx.x * 4 + (threadIdx.x >> 6);
  int lane  = threadIdx.x & 63;
  const float4 v = *(const float4*)(x + (size_t)token*DM + lane*4);
  float s  = v.x + v.y + v.z + v.w;
  float ss = v.x*v.x + v.y*v.y + v.z*v.z + v.w*v.w;
  #pragma unroll
  for (int off = 32; off > 0; off >>= 1) {
    s  += __shfl_xor(s,  off, 64);
    ss += __shfl_xor(ss, off, 64);
  }
  float mean = s * (1.f/DM);
  float var  = ss * (1.f/DM) - mean*mean;
  float rstd = rsqrtf(var + 1e-5f);
  const float4 g = *(const float4*)(gamma + lane*4);
  const float4 b = *(const float4*)(beta  + lane*4);
  ushort4 o;
  o.x = f2bf((v.x - mean)*rstd*g.x + b.x);
  o.y = f2bf((v.y - mean)*rstd*g.y + b.y);
  o.z = f2bf((v.z - mean)*rstd*g.z + b.z);
  o.w = f2bf((v.w - mean)*rstd*g.w + b.w);
  *(ushort4*)(xn + (size_t)token*DM + lane*4) = o;
}

// ---------------- persistent-B MFMA GEMM, 64x64 wave tiles -----------------
// C[M,N] = A[M,K] @ Bw[N,K]^T. Block: 256 thr (4 waves), tile 256M x 64N;
// wave w owns rows w*64..w*64+63 (4 mi tiles) x all 64 N (4 ni tiles).
// LDS: B panel 64 x K bf16 staged once (16B-chunk XOR swizzle) + wave-private
// 32x72 C staging (EPI 1/2). XCD chunk swizzle: grid MUST be (128, GY).
// K-loop per kt: 4 global_load_dwordx4 (A) + 4 ds_read_b128 (B, imm offsets
// off 2 per-lane bases) + 16 MFMA. One barrier per kernel.
template<int EPI, int KSTEPS>
__global__ __launch_bounds__(256, 3) void gemm_ws(
    const unsigned short* __restrict__ A,   // [M,K] bf16
    const unsigned short* __restrict__ Bw,  // [N,K] bf16
    const float* __restrict__ bias,         // [N]
    unsigned short* __restrict__ o_xp, unsigned short* __restrict__ o_z,
    unsigned short* __restrict__ o_dtin,    // EPI=1
    unsigned short* __restrict__ o_bf,      // EPI=2
    const float* __restrict__ resid, float* __restrict__ o_f)  // EPI=3
{
  constexpr int K    = KSTEPS * 32;
  constexpr int CPR  = K / 8;               // 16B chunks per B row
  __shared__ unsigned short sB[64*K];       // 48KB (K=384) / 32KB (K=256)
  __shared__ unsigned short sC[(EPI == 3) ? 2 : 4*32*72];  // wave-private staging

  const int t    = threadIdx.x;
  const int lane = t & 63;
  const int w    = t >> 6;
  const int fr   = lane & 15;
  const int fq   = lane >> 4;
  const int wm   = w * 64;

  // ---- XCD chunk swizzle: bijective for grid (128, GY) ----
  const int q    = blockIdx.y * 128 + blockIdx.x;
  const int bx2  = (q & 7) * 16 + ((q >> 3) & 15);
  const int by2  = q >> 7;
  const int mbase = bx2 * 256;
  const int nbase = by2 * 64;

  // ---- stage B panel (once per block): swizzled 16B chunks ----
  #pragma unroll
  for (int i = 0; i < (64*CPR)/256; ++i) {
    int c   = i*256 + t;
    int row = c / CPR;
    int j   = c - row*CPR;
    int jp  = (j & ~7) | ((j & 7) ^ (row & 7));
    __builtin_amdgcn_global_load_lds(AS1(Bw + (size_t)(nbase + row)*K + jp*8),
                                     AS3(sB + c*8), 16, 0, 0);
  }

  // ---- B LDS read bases: byte addr for (ni,kt) decomposes as
  //   fr*2K + ((fq^(fr&7)) ^ 4*(kt&1))*16  +  ni*32K + (kt>>1)*128
  const unsigned short* sBrE = sB + (size_t)fr*K + ( fq      ^ (fr & 7))*8;
  const unsigned short* sBrO = sB + (size_t)fr*K + ((fq | 4) ^ (fr & 7))*8;

  float bvv[4];
  #pragma unroll
  for (int ni = 0; ni < 4; ++ni) bvv[ni] = bias[nbase + ni*16 + fr];

  unsigned short* sCw = sC + w*(32*72);     // wave-private staging (EPI 1/2)

  __syncthreads();   // B panel resident — the ONLY barrier in this kernel

  f32x4 acc[4][4];
  #pragma unroll
  for (int mi = 0; mi < 4; ++mi)
    #pragma unroll
    for (int ni = 0; ni < 4; ++ni) acc[mi][ni] = (f32x4){0.f, 0.f, 0.f, 0.f};

  #pragma unroll
  for (int kt = 0; kt < KSTEPS; ++kt) {
    s16x8 af[4];
    #pragma unroll
    for (int mi = 0; mi < 4; ++mi)
      af[mi] = *(const s16x8*)(A + (size_t)(mbase + wm + mi*16 + fr)*K + fq*8 + kt*32);
    const unsigned short* bb = (kt & 1) ? sBrO : sBrE;
    s16x8 bfr[4];
    #pragma unroll
    for (int ni = 0; ni < 4; ++ni)
      bfr[ni] = *(const s16x8*)(bb + ni*16*K + (kt >> 1)*64);
    #pragma unroll
    for (int ni = 0; ni < 4; ++ni)
      #pragma unroll
      for (int mi = 0; mi < 4; ++mi)
        acc[mi][ni] = __builtin_amdgcn_mfma_f32_16x16x32_bf16(af[mi], bfr[ni], acc[mi][ni], 0, 0, 0);
  }

  // ---- epilogue: C layout per 16x16 tile: col=fr, row=fq*4+r (m89) ----
  if constexpr (EPI == 3) {
    #pragma unroll
    for (int ni = 0; ni < 4; ++ni) {
      int gn = nbase + ni*16 + fr;
      #pragma unroll
      for (int mi = 0; mi < 4; ++mi) {
        int gm0 = mbase + wm + mi*16 + fq*4;
        #pragma unroll
        for (int r = 0; r < 4; ++r) {
          size_t gm = (size_t)(gm0 + r);
          o_f[gm*DM + gn] = acc[mi][ni][r] + bvv[ni] + resid[gm*DM + gn];
        }
      }
    }
  } else {
    const bool do_silu = (EPI == 1) && (by2 < 12);
    unsigned short* dst;
    int colbase;
    if constexpr (EPI == 1) {
      dst = (by2 < 6) ? o_xp : (by2 < 12) ? o_z : o_dtin;
      colbase = (by2 % 6) * 64;
    } else {
      dst = o_bf; colbase = nbase;
    }
    // two passes over mi-pairs through the 32x72 wave-private buffer.
    // Same-wave DS ops execute in order -> no barriers needed; the store's
    // use of the ds_read value forces the lgkm wait before pass 2 writes.
    #pragma unroll
    for (int p = 0; p < 2; ++p) {
      #pragma unroll
      for (int ni = 0; ni < 4; ++ni) {
        int cn = ni*16 + fr;
        #pragma unroll
        for (int mi2 = 0; mi2 < 2; ++mi2) {
          int rm0 = mi2*16 + fq*4;
          #pragma unroll
          for (int r = 0; r < 4; ++r) {
            float c = acc[p*2 + mi2][ni][r] + bvv[ni];
            if constexpr (EPI == 1) { if (do_silu) c = silu_f(c); }
            else                    { c = (c > 20.f) ? c : __logf(1.f + __expf(c)); }
            sCw[(rm0 + r)*72 + cn] = f2bf(c);
          }
        }
      }
      asm volatile("s_waitcnt lgkmcnt(0)" ::: "memory");
      const int rr = lane >> 3, cc = (lane & 7) * 8;
      #pragma unroll
      for (int it = 0; it < 4; ++it) {
        int row32 = rr + it*8;
        s16x8 v = *(const s16x8*)(sCw + row32*72 + cc);
        *(s16x8*)(dst + (size_t)(mbase + wm + p*32 + row32)*DI + colbase + cc) = v;
      }
    }
  }
}

// ---------------- chunked selective scan ----------------
__global__ __launch_bounds__(384) void scan_kernel(
    const unsigned short* __restrict__ xp, const unsigned short* __restrict__ dt,
    const unsigned short* __restrict__ zb, const float* __restrict__ A_log,
    const float* __restrict__ D_vec, unsigned short* __restrict__ yz) {
  int g  = blockIdx.x;
  int di = threadIdx.x;
  size_t base = (size_t)g * 32 * DI + di;
  float a[DS];
  #pragma unroll
  for (int s = 0; s < DS; ++s) a[s] = -__expf(A_log[di*DS + s]);
  float Dv = D_vec[di];
  float h[DS] = {0.f,0.f,0.f,0.f,0.f,0.f,0.f,0.f};
  for (int tt = 0; tt < 32; ++tt) {
    size_t idx = base + (size_t)tt * DI;
    float xv  = bf2f(xp[idx]);
    float dtv = bf2f(dt[idx]);
    float y = 0.f;
    #pragma unroll
    for (int s = 0; s < DS; ++s) {
      h[s] = h[s] * __expf(dtv * a[s]) + xv;
      y += h[s];
    }
    float zv = bf2f(zb[idx]);
    yz[idx] = f2bf(y * zv + xv * Dv);
  }
}

extern "C" void kernel_launch(void* const* d_in, const int* in_sizes, int n_in,
                              void* d_out, int out_size, void* d_ws, size_t ws_size,
                              hipStream_t stream) {
  const float* x     = (const float*)d_in[0];
  const float* gamma = (const float*)d_in[1];
  const float* beta  = (const float*)d_in[2];
  const float* W_in  = (const float*)d_in[3];
  const float* b_in  = (const float*)d_in[4];
  const float* W_dt  = (const float*)d_in[5];
  const float* b_dt  = (const float*)d_in[6];
  const float* A_log = (const float*)d_in[7];
  const float* D_vec = (const float*)d_in[8];
  const float* W_out = (const float*)d_in[9];
  const float* b_out = (const float*)d_in[10];
  float* out = (float*)d_out;

  char* ws = (char*)d_ws;
  size_t off = 0;
  auto alloc = [&](size_t bytes) -> char* {
    char* p = ws + off; off += (bytes + 255) & ~(size_t)255; return p;
  };
  unsigned short* xn    = (unsigned short*)alloc((size_t)M_*DM*2);
  unsigned short* xpb   = (unsigned short*)alloc((size_t)M_*DI*2);
  unsigned short* zb    = (unsigned short*)alloc((size_t)M_*DI*2);
  unsigned short* dtin  = (unsigned short*)alloc((size_t)M_*DI*2);
  unsigned short* dtb   = (unsigned short*)alloc((size_t)M_*DI*2);
  unsigned short* yzb   = dtin;   // dtin dead after GEMM2 -> reuse for yz
  unsigned short* winb  = (unsigned short*)alloc((size_t)3*DI*DM*2);
  unsigned short* wdtb  = (unsigned short*)alloc((size_t)DI*DI*2);
  unsigned short* woutb = (unsigned short*)alloc((size_t)DM*DI*2);

  cvt_kernel<<<dim3((3*DI*DM + 255)/256), 256, 0, stream>>>(W_in, W_dt, W_out, winb, wdtb, woutb);
  ln_kernel<<<dim3(M_/4), 256, 0, stream>>>(x, gamma, beta, xn);
  // GEMM1: xn[M,256] @ W_in[1152,256]^T -> silu(xp), silu(z), dtin
  gemm_ws<1, 8><<<dim3(128, (3*DI)/64), 256, 0, stream>>>(
      xn, winb, b_in, xpb, zb, dtin, nullptr, nullptr, nullptr);
  // GEMM2: dtin[M,384] @ W_dt[384,384]^T ; softplus -> dt
  gemm_ws<2, 12><<<dim3(128, DI/64), 256, 0, stream>>>(
      dtin, wdtb, b_dt, nullptr, nullptr, nullptr, dtb, nullptr, nullptr);
  // scan -> yz = y*z + xp*D
  scan_kernel<<<dim3(M_/32), DI, 0, stream>>>(xpb, dtb, zb, A_log, D_vec, yzb);
  // GEMM3: yz[M,384] @ W_out[256,384]^T + b_out + residual -> out (fp32)
  gemm_ws<3, 12><<<dim3(128, DM/64), 256, 0, stream>>>(
      yzb, woutb, b_out, nullptr, nullptr, nullptr, nullptr, x, out);
}

// Round 10
// 217.369 us; speedup vs baseline: 1.1839x; 1.0327x over previous
//
#include <hip/hip_runtime.h>
#include <stdint.h>

// S6Layer on MI355X. B=8, L=4096, DM=256, DI=384, DS=8, CHUNK=32.
// R16 (this round):
//  1. REVERT GEMM template to R12 geometry (measured best: GEMM1 50.9us vs
//     R15's 58.5 - the 64x64 wave tile regressed; compiler VGPR-capped at 84
//     and serialized within kt. MfmaUtil has been 12-15% across ALL schedule
//     variants -> stop pulling that lever).
//  2. ALGEBRA: dt_in is a LINEAR slice (no activation between the two GEMMs):
//       dt_arg = xn @ (W_dt@W_in_dt)^T + (W_dt@b_in_dt + b_dt)
//     Precompute W_eff[384,256] (fp32, tiny prep kernel) into winb's dt-slice
//     and b_eff into a combined bias; GEMM1's dt panels apply softplus in the
//     epilogue and write dt directly. GEMM2 (~50-60us) + dtin 48MB round-trip
//     ELIMINATED. Scan writes yz in-place over dt (same thread+index, RAW-safe).
// Pipeline: cvt, prep, ln, GEMM1(xp/z/dt), scan(in-place), GEMM3.
// R12 kept: persistent-B MT=2, XCD chunk swizzle (grid (128,GY)), 1 barrier,
// B swizzle folded to 2 bases+imm, wave-private epilogue staging pad 72.
#define B_  8
#define L_  4096
#define DM  256
#define DI  384
#define DS  8
#define M_  (B_*L_)   // 32768 tokens

typedef float f32x4 __attribute__((ext_vector_type(4)));
typedef short s16x8 __attribute__((ext_vector_type(8)));

#define AS1(p) ((__attribute__((address_space(1))) void*)(p))
#define AS3(p) ((__attribute__((address_space(3))) void*)(p))

__device__ __forceinline__ unsigned short f2bf(float f) {
  union { float f; uint32_t u; } v; v.f = f;
  uint32_t r = v.u + 0x7FFFu + ((v.u >> 16) & 1u);   // RNE
  return (unsigned short)(r >> 16);
}
__device__ __forceinline__ float bf2f(unsigned short h) {
  union { uint32_t u; float f; } v; v.u = ((uint32_t)h) << 16;
  return v.f;
}
__device__ __forceinline__ float silu_f(float x) {
  return x * __builtin_amdgcn_rcpf(1.f + __expf(-x));
}

// ---------------- weight fp32 -> bf16 (+ b_in copy into combined bias) -----
__global__ __launch_bounds__(256) void cvt_kernel(
    const float* __restrict__ w0, const float* __restrict__ w2,
    const float* __restrict__ b_in,
    unsigned short* __restrict__ o0, unsigned short* __restrict__ o2,
    float* __restrict__ biasc) {
  int i = blockIdx.x * 256 + threadIdx.x;
  if (i < 3*DI*DM) o0[i] = f2bf(w0[i]);
  if (i < DM*DI)   o2[i] = f2bf(w2[i]);
  if (i < 2*DI)    biasc[i] = b_in[i];
}

// ---------------- prep: W_eff = W_dt @ W_in_dt, b_eff = W_dt@b_in_dt + b_dt
// grid 386 x 256. Blocks [0,384): W_eff row nb (threads = 256 output cols,
// coalesced W_in row reads, W_dt scalar broadcast). Blocks 384/385: b_eff.
__global__ __launch_bounds__(256) void prep_kernel(
    const float* __restrict__ W_in, const float* __restrict__ b_in,
    const float* __restrict__ W_dt, const float* __restrict__ b_dt,
    unsigned short* __restrict__ winb, float* __restrict__ biasc) {
  int nb = blockIdx.x;
  if (nb < DI) {
    int c = threadIdx.x;                 // 0..DM-1
    float acc = 0.f;
    for (int k = 0; k < DI; ++k)
      acc += W_dt[(size_t)nb*DI + k] * W_in[(size_t)(2*DI + k)*DM + c];
    winb[(size_t)(2*DI + nb)*DM + c] = f2bf(acc);
  } else {
    int n = (nb - DI)*256 + threadIdx.x;
    if (n < DI) {
      float acc = b_dt[n];
      for (int k = 0; k < DI; ++k)
        acc += W_dt[(size_t)n*DI + k] * b_in[2*DI + k];
      biasc[2*DI + n] = acc;
    }
  }
}

// ---------------- layernorm: one wave per token ----------------
__global__ __launch_bounds__(256) void ln_kernel(
    const float* __restrict__ x, const float* __restrict__ gamma, const float* __restrict__ beta,
    unsigned short* __restrict__ xn) {
  int token = blockIdx.x * 4 + (threadIdx.x >> 6);
  int lane  = threadIdx.x & 63;
  const float4 v = *(const float4*)(x + (size_t)token*DM + lane*4);
  float s  = v.x + v.y + v.z + v.w;
  float ss = v.x*v.x + v.y*v.y + v.z*v.z + v.w*v.w;
  #pragma unroll
  for (int off = 32; off > 0; off >>= 1) {
    s  += __shfl_xor(s,  off, 64);
    ss += __shfl_xor(ss, off, 64);
  }
  float mean = s * (1.f/DM);
  float var  = ss * (1.f/DM) - mean*mean;
  float rstd = rsqrtf(var + 1e-5f);
  const float4 g = *(const float4*)(gamma + lane*4);
  const float4 b = *(const float4*)(beta  + lane*4);
  ushort4 o;
  o.x = f2bf((v.x - mean)*rstd*g.x + b.x);
  o.y = f2bf((v.y - mean)*rstd*g.y + b.y);
  o.z = f2bf((v.z - mean)*rstd*g.z + b.z);
  o.w = f2bf((v.w - mean)*rstd*g.w + b.w);
  *(ushort4*)(xn + (size_t)token*DM + lane*4) = o;
}

// ---------------- persistent-B MFMA GEMM (R12 geometry), MT M-tiles --------
// C[M,N] = A[M,K] @ Bw[N,K]^T. Block: 256 thr (4 waves), tile 128M x 64N;
// wave w owns rows w*32..w*32+31 (2 mi tiles) x all 64 N (4 ni tiles).
// EPI=1: panels 0-5 silu->xp, 6-11 silu->z, 12-17 softplus->dt.
// EPI=3: + b_out + residual -> fp32 out.
template<int EPI, int KSTEPS, int MT>
__global__ __launch_bounds__(256, 3) void gemm_ws(
    const unsigned short* __restrict__ A,   // [M,K] bf16
    const unsigned short* __restrict__ Bw,  // [N,K] bf16
    const float* __restrict__ bias,         // [N]
    unsigned short* __restrict__ o_xp, unsigned short* __restrict__ o_z,
    unsigned short* __restrict__ o_dt,      // EPI=1
    const float* __restrict__ resid, float* __restrict__ o_f)  // EPI=3
{
  constexpr int K    = KSTEPS * 32;
  constexpr int CPR  = K / 8;               // 16B chunks per B row
  __shared__ unsigned short sB[64*K];
  __shared__ unsigned short sC[(EPI == 3) ? 2 : 4*32*72];  // wave-private staging

  const int t    = threadIdx.x;
  const int lane = t & 63;
  const int w    = t >> 6;
  const int fr   = lane & 15;
  const int fq   = lane >> 4;
  const int wm   = w * 32;

  // ---- XCD chunk swizzle: bijective for grid (128, GY) ----
  const int q    = blockIdx.y * 128 + blockIdx.x;
  const int bx2  = (q & 7) * 16 + ((q >> 3) & 15);
  const int by2  = q >> 7;
  const int mbase0 = bx2 * (128 * MT);
  const int nbase  = by2 * 64;

  // ---- stage B panel (once per block): swizzled 16B chunks ----
  #pragma unroll
  for (int i = 0; i < (64*CPR)/256; ++i) {
    int c   = i*256 + t;
    int row = c / CPR;
    int j   = c - row*CPR;
    int jp  = (j & ~7) | ((j & 7) ^ (row & 7));
    __builtin_amdgcn_global_load_lds(AS1(Bw + (size_t)(nbase + row)*K + jp*8),
                                     AS3(sB + c*8), 16, 0, 0);
  }

  const unsigned short* sBrE = sB + (size_t)fr*K + ( fq      ^ (fr & 7))*8;
  const unsigned short* sBrO = sB + (size_t)fr*K + ((fq | 4) ^ (fr & 7))*8;

  float bvv[4];
  #pragma unroll
  for (int ni = 0; ni < 4; ++ni) bvv[ni] = bias[nbase + ni*16 + fr];

  unsigned short* sCw = sC + w*(32*72);

  __syncthreads();   // B panel resident — the ONLY barrier in this kernel

  #pragma unroll
  for (int mt = 0; mt < MT; ++mt) {
    const int mbase = mbase0 + mt*128;
    const unsigned short* gA0 = A + (size_t)(mbase + wm + fr)*K + fq*8;
    const unsigned short* gA1 = gA0 + (size_t)16*K;

    f32x4 acc[2][4];
    #pragma unroll
    for (int mi = 0; mi < 2; ++mi)
      #pragma unroll
      for (int ni = 0; ni < 4; ++ni) acc[mi][ni] = (f32x4){0.f, 0.f, 0.f, 0.f};

    #pragma unroll
    for (int kt = 0; kt < KSTEPS; ++kt) {
      s16x8 a0 = *(const s16x8*)(gA0 + kt*32);
      s16x8 a1 = *(const s16x8*)(gA1 + kt*32);
      const unsigned short* bb = (kt & 1) ? sBrO : sBrE;
      s16x8 bfr[4];
      #pragma unroll
      for (int ni = 0; ni < 4; ++ni)
        bfr[ni] = *(const s16x8*)(bb + ni*16*K + (kt >> 1)*64);
      #pragma unroll
      for (int ni = 0; ni < 4; ++ni) {
        acc[0][ni] = __builtin_amdgcn_mfma_f32_16x16x32_bf16(a0, bfr[ni], acc[0][ni], 0, 0, 0);
        acc[1][ni] = __builtin_amdgcn_mfma_f32_16x16x32_bf16(a1, bfr[ni], acc[1][ni], 0, 0, 0);
      }
    }

    // ---- epilogue: C layout per 16x16 tile: col=fr, row=fq*4+r (m89) ----
    if constexpr (EPI == 3) {
      #pragma unroll
      for (int ni = 0; ni < 4; ++ni) {
        int gn = nbase + ni*16 + fr;
        #pragma unroll
        for (int mi = 0; mi < 2; ++mi) {
          int gm0 = mbase + wm + mi*16 + fq*4;
          #pragma unroll
          for (int r = 0; r < 4; ++r) {
            size_t gm = (size_t)(gm0 + r);
            o_f[gm*DM + gn] = acc[mi][ni][r] + bvv[ni] + resid[gm*DM + gn];
          }
        }
      }
    } else {
      const bool do_silu = (by2 < 12);      // 0-11 silu; 12-17 softplus (dt)
      #pragma unroll
      for (int ni = 0; ni < 4; ++ni) {
        int cn = ni*16 + fr;
        #pragma unroll
        for (int mi = 0; mi < 2; ++mi) {
          int rm0 = mi*16 + fq*4;
          #pragma unroll
          for (int r = 0; r < 4; ++r) {
            float c = acc[mi][ni][r] + bvv[ni];
            c = do_silu ? silu_f(c)
                        : ((c > 20.f) ? c : __logf(1.f + __expf(c)));
            sCw[(rm0 + r)*72 + cn] = f2bf(c);
          }
        }
      }
      asm volatile("s_waitcnt lgkmcnt(0)" ::: "memory");
      unsigned short* dst = (by2 < 6) ? o_xp : (by2 < 12) ? o_z : o_dt;
      int colbase = (by2 % 6) * 64;
      const int rr = lane >> 3, cc = (lane & 7) * 8;
      #pragma unroll
      for (int it = 0; it < 4; ++it) {
        int row32 = rr + it*8;
        s16x8 v = *(const s16x8*)(sCw + row32*72 + cc);
        *(s16x8*)(dst + (size_t)(mbase + wm + row32)*DI + colbase + cc) = v;
      }
    }
  }
}

// ---------------- chunked selective scan (yz in-place over dt) -------------
__global__ __launch_bounds__(384) void scan_kernel(
    const unsigned short* __restrict__ xp, unsigned short* dt_yz,
    const unsigned short* __restrict__ zb, const float* __restrict__ A_log,
    const float* __restrict__ D_vec) {
  int g  = blockIdx.x;
  int di = threadIdx.x;
  size_t base = (size_t)g * 32 * DI + di;
  float a[DS];
  #pragma unroll
  for (int s = 0; s < DS; ++s) a[s] = -__expf(A_log[di*DS + s]);
  float Dv = D_vec[di];
  float h[DS] = {0.f,0.f,0.f,0.f,0.f,0.f,0.f,0.f};
  for (int tt = 0; tt < 32; ++tt) {
    size_t idx = base + (size_t)tt * DI;
    float xv  = bf2f(xp[idx]);
    float dtv = bf2f(dt_yz[idx]);
    float y = 0.f;
    #pragma unroll
    for (int s = 0; s < DS; ++s) {
      h[s] = h[s] * __expf(dtv * a[s]) + xv;
      y += h[s];
    }
    float zv = bf2f(zb[idx]);
    dt_yz[idx] = f2bf(y * zv + xv * Dv);   // same idx, after the read: safe
  }
}

extern "C" void kernel_launch(void* const* d_in, const int* in_sizes, int n_in,
                              void* d_out, int out_size, void* d_ws, size_t ws_size,
                              hipStream_t stream) {
  const float* x     = (const float*)d_in[0];
  const float* gamma = (const float*)d_in[1];
  const float* beta  = (const float*)d_in[2];
  const float* W_in  = (const float*)d_in[3];
  const float* b_in  = (const float*)d_in[4];
  const float* W_dt  = (const float*)d_in[5];
  const float* b_dt  = (const float*)d_in[6];
  const float* A_log = (const float*)d_in[7];
  const float* D_vec = (const float*)d_in[8];
  const float* W_out = (const float*)d_in[9];
  const float* b_out = (const float*)d_in[10];
  float* out = (float*)d_out;

  char* ws = (char*)d_ws;
  size_t off = 0;
  auto alloc = [&](size_t bytes) -> char* {
    char* p = ws + off; off += (bytes + 255) & ~(size_t)255; return p;
  };
  unsigned short* xn    = (unsigned short*)alloc((size_t)M_*DM*2);
  unsigned short* xpb   = (unsigned short*)alloc((size_t)M_*DI*2);
  unsigned short* zb    = (unsigned short*)alloc((size_t)M_*DI*2);
  unsigned short* dtb   = (unsigned short*)alloc((size_t)M_*DI*2);  // dt, then yz in-place
  unsigned short* winb  = (unsigned short*)alloc((size_t)3*DI*DM*2);
  unsigned short* woutb = (unsigned short*)alloc((size_t)DM*DI*2);
  float*          biasc = (float*)alloc((size_t)3*DI*4);

  cvt_kernel<<<dim3((3*DI*DM + 255)/256), 256, 0, stream>>>(W_in, W_out, b_in, winb, woutb, biasc);
  prep_kernel<<<dim3(DI + 2), 256, 0, stream>>>(W_in, b_in, W_dt, b_dt, winb, biasc);
  ln_kernel<<<dim3(M_/4), 256, 0, stream>>>(x, gamma, beta, xn);
  // GEMM1: xn[M,256] @ [W_in_xz ; W_eff][1152,256]^T -> silu xp, silu z, softplus dt
  gemm_ws<1, 8, 2><<<dim3(128, (3*DI)/64), 256, 0, stream>>>(
      xn, winb, biasc, xpb, zb, dtb, nullptr, nullptr);
  // scan: yz = y*z + xp*D, in-place over dtb
  scan_kernel<<<dim3(M_/32), DI, 0, stream>>>(xpb, dtb, zb, A_log, D_vec);
  // GEMM3: yz[M,384] @ W_out[256,384]^T + b_out + residual -> out (fp32)
  gemm_ws<3, 12, 2><<<dim3(128, DM/64), 256, 0, stream>>>(
      dtb, woutb, b_out, nullptr, nullptr, nullptr, x, out);
}